// Round 19
// baseline (138.765 us; speedup 1.0000x reference)
//
#include <hip/hip_runtime.h>
#include <hip/hip_bf16.h>
#include <cstdint>
#include <cstddef>

#define B_ 2
#define T_ 2048
#define C_ 1024
#define H_ 16
#define D_ 64

typedef unsigned short u16;
typedef unsigned int u32;

typedef __bf16 bf16x8 __attribute__((ext_vector_type(8)));
typedef float f32x4 __attribute__((ext_vector_type(4)));

// 0.125 (1/sqrt(64)) * log2(e): QK^T then produces log2-domain scores
#define QSCALE 0.18033688011112042f
#define DEFER_THR 11.5f

union BFQ {
    uint4 q;
    bf16x8 v;
    u16 s[8];
};

__device__ __forceinline__ float bf2f(u16 s) {
    union { u32 u; float f; } x;
    x.u = ((u32)s) << 16;
    return x.f;
}

__device__ __forceinline__ u16 f2bf(float f) {  // HW RTNE
    union { __bf16 h; u16 u; } c;
    c.h = (__bf16)f;
    return c.u;
}

__device__ __forceinline__ void gl_lds16(const u16* g, u16* l) {
    __builtin_amdgcn_global_load_lds(
        (const __attribute__((address_space(1))) u32*)g,
        (__attribute__((address_space(3))) u32*)l, 16, 0, 0);
}

// ---------------- fp32 -> bf16 conversion: all 7 tensors in one launch ----------------
__global__ void cvt7_kernel(const float* __restrict__ q, const float* __restrict__ k,
                            const float* __restrict__ v, const float* __restrict__ Wq,
                            const float* __restrict__ Wk, const float* __restrict__ Wv,
                            const float* __restrict__ Wo,
                            u16* __restrict__ qb, u16* __restrict__ kb, u16* __restrict__ vb,
                            u16* __restrict__ Wqb, u16* __restrict__ Wkb, u16* __restrict__ Wvb,
                            u16* __restrict__ Wob, int nBig4, int nW4) {
    int z = blockIdx.z;
    const float* in;
    u16* out;
    int n4;
    switch (z) {
        case 0: in = q;  out = qb;  n4 = nBig4; break;
        case 1: in = k;  out = kb;  n4 = nBig4; break;
        case 2: in = v;  out = vb;  n4 = nBig4; break;
        case 3: in = Wq; out = Wqb; n4 = nW4; break;
        case 4: in = Wk; out = Wkb; n4 = nW4; break;
        case 5: in = Wv; out = Wvb; n4 = nW4; break;
        default: in = Wo; out = Wob; n4 = nW4; break;
    }
    int i = blockIdx.x * blockDim.x + threadIdx.x;
    int stride = gridDim.x * blockDim.x;
    for (; i < n4; i += stride) {
        float4 f = reinterpret_cast<const float4*>(in)[i];
        ushort4 o;
        o.x = f2bf(f.x);
        o.y = f2bf(f.y);
        o.z = f2bf(f.z);
        o.w = f2bf(f.w);
        reinterpret_cast<ushort4*>(out)[i] = o;
    }
}

// ---------------- GEMM body (R6 config): C[m,n] = sum_k A[m,k]*Bw[n,k] + bias[n]
// BM=128, BN=64, BK=64. 2-phase double-buffered LDS, both-sides XOR swizzle.
template <int OUT_BF16>
__device__ __forceinline__ void gemm_body(const u16* __restrict__ A,
                                          const u16* __restrict__ Bw,
                                          const float* __restrict__ bias,
                                          void* __restrict__ Cout,
                                          int M, int N, int K) {
    __shared__ u16 As[2][128 * 64];
    __shared__ u16 Bs[2][64 * 64];

    const int tid = threadIdx.x;
    const int lane = tid & 63;
    const int wave = tid >> 6;
    const int wm = wave >> 1, wn = wave & 1;
    const int g = lane >> 4, r = lane & 15;
    const int m0 = blockIdx.y * 128, n0 = blockIdx.x * 64;

    f32x4 acc[4][2] = {};

    const int lrow = lane >> 3;
    const int lcolS = ((lane & 7) ^ (lane >> 3)) * 8;
    const u16* Abase = A + (size_t)(m0 + lrow) * K + lcolS;
    const u16* Bbase = Bw + (size_t)(n0 + lrow) * K + lcolS;

#pragma unroll
    for (int c = 0; c < 4; ++c) {
        int ca = 4 * wave + c;
        gl_lds16(Abase + (size_t)(8 * ca) * K, As[0] + ca * 512);
    }
#pragma unroll
    for (int c = 0; c < 2; ++c) {
        int cb = 2 * wave + c;
        gl_lds16(Bbase + (size_t)(8 * cb) * K, Bs[0] + cb * 512);
    }
    __syncthreads();

    int cur = 0;
    for (int k0 = 0; k0 < K; k0 += 64) {
        if (k0 + 64 < K) {
#pragma unroll
            for (int c = 0; c < 4; ++c) {
                int ca = 4 * wave + c;
                gl_lds16(Abase + (size_t)(8 * ca) * K + k0 + 64, As[cur ^ 1] + ca * 512);
            }
#pragma unroll
            for (int c = 0; c < 2; ++c) {
                int cb = 2 * wave + c;
                gl_lds16(Bbase + (size_t)(8 * cb) * K + k0 + 64, Bs[cur ^ 1] + cb * 512);
            }
        }

#pragma unroll
        for (int kk = 0; kk < 2; ++kk) {
            bf16x8 af[4], bfv[2];
#pragma unroll
            for (int mt = 0; mt < 4; ++mt) {
                int row = wm * 64 + mt * 16 + r;
                BFQ u;
                u.q = *(const uint4*)(As[cur] + row * 64 + (((kk * 4 + g) ^ (r & 7)) * 8));
                af[mt] = u.v;
            }
#pragma unroll
            for (int nt = 0; nt < 2; ++nt) {
                int row = wn * 32 + nt * 16 + r;
                BFQ u;
                u.q = *(const uint4*)(Bs[cur] + row * 64 + (((kk * 4 + g) ^ (r & 7)) * 8));
                bfv[nt] = u.v;
            }
            __builtin_amdgcn_s_setprio(1);
#pragma unroll
            for (int mt = 0; mt < 4; ++mt)
#pragma unroll
                for (int nt = 0; nt < 2; ++nt)
                    acc[mt][nt] = __builtin_amdgcn_mfma_f32_16x16x32_bf16(af[mt], bfv[nt], acc[mt][nt], 0, 0, 0);
            __builtin_amdgcn_s_setprio(0);
        }
        __syncthreads();
        cur ^= 1;
    }

#pragma unroll
    for (int mt = 0; mt < 4; ++mt) {
#pragma unroll
        for (int nt = 0; nt < 2; ++nt) {
            int n = n0 + wn * 32 + nt * 16 + r;
            float bv = bias[n];
#pragma unroll
            for (int j = 0; j < 4; ++j) {
                int m = m0 + wm * 64 + mt * 16 + g * 4 + j;
                float val = acc[mt][nt][j] + bv;
                if (OUT_BF16)
                    ((u16*)Cout)[(size_t)m * N + n] = f2bf(val);
                else
                    ((float*)Cout)[(size_t)m * N + n] = val;
            }
        }
    }
}

__global__ __launch_bounds__(256, 3) void gemm3_kernel(
    const u16* __restrict__ A0, const u16* __restrict__ A1, const u16* __restrict__ A2,
    const u16* __restrict__ W0, const u16* __restrict__ W1, const u16* __restrict__ W2,
    const float* __restrict__ b0, const float* __restrict__ b1, const float* __restrict__ b2,
    u16* __restrict__ C0, u16* __restrict__ C1, u16* __restrict__ C2,
    int M, int N, int K) {
    int z = blockIdx.z;
    const u16* A = z == 0 ? A0 : (z == 1 ? A1 : A2);
    const u16* W = z == 0 ? W0 : (z == 1 ? W1 : W2);
    const float* bias = z == 0 ? b0 : (z == 1 ? b1 : b2);
    u16* C = z == 0 ? C0 : (z == 1 ? C1 : C2);
    gemm_body<1>(A, W, bias, C, M, N, K);
}

__global__ __launch_bounds__(256, 3) void gemm_f32_kernel(const u16* __restrict__ A,
                                                          const u16* __restrict__ W,
                                                          const float* __restrict__ bias,
                                                          float* __restrict__ C,
                                                          int M, int N, int K) {
    gemm_body<0>(A, W, bias, C, M, N, K);
}

// ---------------- causal flash attention (R18 + single-barrier Vt dbuf) -------------
// 1D grid 1024, XCD-decoded (T1). Balanced pairing (i, 31-i). Split-KV z + merge.
// Swapped QK^T, deferred-l softmax, per-chain PV interleave (shared per-wave Pl).
// NEW: Vt double-buffered -> ONE barrier per KV iteration (was 2). Tile-n V/K are
// written during iter n-1 (disjoint per-thread regions); the end-of-iter barrier
// plus per-wave vmcnt(0)/lgkm drains makes them visible. Reads of buffer b at
// iter n-1 complete (register delivery forced by lgkmcnt before pre-barrier MFMA
// uses) before any wave's post-barrier writes to b at iter n.

__device__ __forceinline__ void softmax_swapped(f32x4* s, int domask, int kv0, int qcol0,
                                                int g, int r, float& m_run, float& l_run,
                                                f32x4* o_acc, u16* pl) {
    float sv[4][4];
#pragma unroll
    for (int nt = 0; nt < 4; ++nt) {
#pragma unroll
        for (int j = 0; j < 4; ++j) {
            float x = s[nt][j];
            if (domask) {
                int kg = kv0 + nt * 16 + g * 4 + j;
                int qg = qcol0 + r;
                x = (kg <= qg) ? x : -1e30f;
            }
            sv[nt][j] = x;
        }
    }
    // per-lane max over this lane's 16 values (all belong to q = qcol0 + r)
    float t0 = fmaxf(fmaxf(sv[0][0], sv[0][1]), fmaxf(sv[0][2], sv[0][3]));
    float t1 = fmaxf(fmaxf(sv[1][0], sv[1][1]), fmaxf(sv[1][2], sv[1][3]));
    float t2 = fmaxf(fmaxf(sv[2][0], sv[2][1]), fmaxf(sv[2][2], sv[2][3]));
    float t3 = fmaxf(fmaxf(sv[3][0], sv[3][1]), fmaxf(sv[3][2], sv[3][3]));
    float lmax = fmaxf(fmaxf(t0, t1), fmaxf(t2, t3));

    if (!__all(lmax - m_run <= DEFER_THR)) {
        float rm = lmax;
        rm = fmaxf(rm, __shfl_xor(rm, 16));
        rm = fmaxf(rm, __shfl_xor(rm, 32));
        float mnew = fmaxf(m_run, rm);
        float fac = __builtin_amdgcn_exp2f(m_run - mnew);
        l_run *= fac;
        m_run = mnew;
#pragma unroll
        for (int j = 0; j < 4; ++j) {
            float fo = __shfl(fac, g * 4 + j);
#pragma unroll
            for (int nt = 0; nt < 4; ++nt) o_acc[nt][j] *= fo;
        }
    }

    float p[4][4];
#pragma unroll
    for (int nt = 0; nt < 4; ++nt)
#pragma unroll
        for (int j = 0; j < 4; ++j)
            p[nt][j] = __builtin_amdgcn_exp2f(sv[nt][j] - m_run);

    float s0 = (p[0][0] + p[0][1]) + (p[0][2] + p[0][3]);
    float s1 = (p[1][0] + p[1][1]) + (p[1][2] + p[1][3]);
    float s2 = (p[2][0] + p[2][1]) + (p[2][2] + p[2][3]);
    float s3 = (p[3][0] + p[3][1]) + (p[3][2] + p[3][3]);
    l_run += (s0 + s1) + (s2 + s3);

    const int sw = (r & 7) << 3;
#pragma unroll
    for (int nt = 0; nt < 4; ++nt) {
        uint2 w;
        w.x = (u32)f2bf(p[nt][0]) | ((u32)f2bf(p[nt][1]) << 16);
        w.y = (u32)f2bf(p[nt][2]) | ((u32)f2bf(p[nt][3]) << 16);
        *(uint2*)&pl[(r * 64 + nt * 16 + g * 4) ^ sw] = w;
    }
}

__global__ __launch_bounds__(256, 2) void attn_kernel(const u16* __restrict__ Qp,
                                                      const u16* __restrict__ Kp,
                                                      const u16* __restrict__ Vp,
                                                      u16* __restrict__ OP0,
                                                      u16* __restrict__ OP1,
                                                      float* __restrict__ ML) {
    __shared__ u16 Kl[2][64 * 64];   // 16KB K double-buffer
    __shared__ u16 Vt[2][64 * 64];   // 16KB V double-buffer (transposed, swizzled)
    __shared__ u16 Pl[4][16 * 64];   // 8KB per-wave P buffer (both chains)

    const int tid = threadIdx.x, lane = tid & 63, wave = tid >> 6;
    const int g = lane >> 4, r = lane & 15;

    const int lid = blockIdx.x;
    const int xcd = lid & 7;
    const int idx = lid >> 3;
    const int bh = xcd * 4 + (idx >> 5);
    const int iz = idx & 31;
    const int i = iz & 15;
    const int z = iz >> 4;
    const int b = bh >> 4, h = bh & 15;
    const int qA0 = i * 64;
    const int qB0 = (31 - i) * 64;

    const u16* Qbh = Qp + ((size_t)b * T_) * C_ + h * 64;
    const u16* Kbh = Kp + ((size_t)b * T_) * C_ + h * 64;
    const u16* Vbh = Vp + ((size_t)b * T_) * C_ + h * 64;

    bf16x8 aqA[2], aqB[2];
    {
        const u16* qa = Qbh + (size_t)(qA0 + wave * 16 + r) * C_ + g * 8;
        const u16* qb = Qbh + (size_t)(qB0 + wave * 16 + r) * C_ + g * 8;
        BFQ u0, u1, u2, u3;
        u0.q = *(const uint4*)(qa);
        u1.q = *(const uint4*)(qa + 32);
        u2.q = *(const uint4*)(qb);
        u3.q = *(const uint4*)(qb + 32);
#pragma unroll
        for (int e = 0; e < 8; ++e) {
            u0.s[e] = f2bf(bf2f(u0.s[e]) * QSCALE);
            u1.s[e] = f2bf(bf2f(u1.s[e]) * QSCALE);
            u2.s[e] = f2bf(bf2f(u2.s[e]) * QSCALE);
            u3.s[e] = f2bf(bf2f(u3.s[e]) * QSCALE);
        }
        aqA[0] = u0.v; aqA[1] = u1.v;
        aqB[0] = u2.v; aqB[1] = u3.v;
    }

    float mA = -1e30f, lA = 0.f, mB = -1e30f, lB = 0.f;
    f32x4 oA[4] = {}, oB[4] = {};

    const int klr = lane >> 3;
    const int kgcol = ((lane & 7) ^ klr) * 8;

    const int vp = tid & 31;
    const int vd0 = (tid >> 5) * 8;

    // ---- prologue: Kl[0] = K(z64); Vt[0] = V(z64); v-regs = V(z64+128) ----
#pragma unroll
    for (int c = 0; c < 2; ++c) {
        int rb = wave * 16 + c * 8;
        gl_lds16(Kbh + (size_t)(z * 64 + rb + klr) * C_ + kgcol, Kl[0] + rb * 64);
    }
    BFQ va, vb;
    {
        const u16* vr0 = Vbh + (size_t)(z * 64 + 2 * vp) * C_ + vd0;
        va.q = *(const uint4*)(vr0);
        vb.q = *(const uint4*)(vr0 + C_);
    }
#pragma unroll
    for (int ii = 0; ii < 8; ++ii) {
        int d = vd0 + ii;
        u32 pr = (u32)va.s[ii] | ((u32)vb.s[ii] << 16);
        *(u32*)&Vt[0][(d * 64 + 2 * vp) ^ ((d & 7) << 3)] = pr;
    }
    {
        // always memory-legal: z*64+128+63 <= 255 < T
        const u16* vr0 = Vbh + (size_t)(z * 64 + 128 + 2 * vp) * C_ + vd0;
        va.q = *(const uint4*)(vr0);
        vb.q = *(const uint4*)(vr0 + C_);
    }
    asm volatile("s_waitcnt vmcnt(0) lgkmcnt(0)" ::: "memory");
    __builtin_amdgcn_s_barrier();

    int cur = 0;
    for (int kv0 = z * 64; kv0 <= qB0; kv0 += 128) {
        const int actA = (kv0 <= qA0);
        const int havenext = (kv0 + 128 <= qB0);

        // Vt[cur] = V(kv0), Kl[cur] = K(kv0) visible (barrier at prev iter end)

        if (havenext) {
            // write Vt[cur^1] = V(kv0+128) from prefetched regs
#pragma unroll
            for (int ii = 0; ii < 8; ++ii) {
                int d = vd0 + ii;
                u32 pr = (u32)va.s[ii] | ((u32)vb.s[ii] << 16);
                *(u32*)&Vt[cur ^ 1][(d * 64 + 2 * vp) ^ ((d & 7) << 3)] = pr;
            }
            if (kv0 + 256 <= qB0) {
                const u16* vr0 = Vbh + (size_t)(kv0 + 256 + 2 * vp) * C_ + vd0;
                va.q = *(const uint4*)(vr0);
                vb.q = *(const uint4*)(vr0 + C_);
            }
            // stage Kl[cur^1] = K(kv0+128)
#pragma unroll
            for (int c = 0; c < 2; ++c) {
                int rb = wave * 16 + c * 8;
                gl_lds16(Kbh + (size_t)(kv0 + 128 + rb + klr) * C_ + kgcol, Kl[cur ^ 1] + rb * 64);
            }
        }

        // K fragments from LDS (swizzled b128 reads)
        BFQ kf[2][4];
#pragma unroll
        for (int kk = 0; kk < 2; ++kk)
#pragma unroll
            for (int nt = 0; nt < 4; ++nt)
                kf[kk][nt].q = *(const uint4*)(Kl[cur] + (nt * 16 + r) * 64 + (((kk * 4 + g) ^ (r & 7)) * 8));

        // swapped QK^T, both chains (shared kf)
        f32x4 sB[4] = {}, sA[4] = {};
        __builtin_amdgcn_s_setprio(1);
#pragma unroll
        for (int kk = 0; kk < 2; ++kk)
#pragma unroll
            for (int nt = 0; nt < 4; ++nt)
                sB[nt] = __builtin_amdgcn_mfma_f32_16x16x32_bf16(kf[kk][nt].v, aqB[kk], sB[nt], 0, 0, 0);
        if (actA) {
#pragma unroll
            for (int kk = 0; kk < 2; ++kk)
#pragma unroll
                for (int nt = 0; nt < 4; ++nt)
                    sA[nt] = __builtin_amdgcn_mfma_f32_16x16x32_bf16(kf[kk][nt].v, aqA[kk], sA[nt], 0, 0, 0);
        }
        __builtin_amdgcn_s_setprio(0);

        // chain B softmax -> Pl[wave]
        softmax_swapped(sB, kv0 == qB0, kv0, qB0 + wave * 16, g, r, mB, lB, oB, Pl[wave]);

        // V fragments from Vt[cur] (visible since iteration start)
        bf16x8 vf[2][4];
#pragma unroll
        for (int kk = 0; kk < 2; ++kk)
#pragma unroll
            for (int nt = 0; nt < 4; ++nt) {
                int d = nt * 16 + r;
                BFQ u;
                u.q = *(const uint4*)&Vt[cur][(d * 64 + kk * 32 + g * 8) ^ ((d & 7) << 3)];
                vf[kk][nt] = u.v;
            }

        asm volatile("s_waitcnt lgkmcnt(0)" ::: "memory");  // P-B + vf delivered

        __builtin_amdgcn_s_setprio(1);
#pragma unroll
        for (int kk = 0; kk < 2; ++kk) {
            BFQ ua;
            ua.q = *(const uint4*)&Pl[wave][(r * 64 + kk * 32 + g * 8) ^ ((r & 7) << 3)];
#pragma unroll
            for (int nt = 0; nt < 4; ++nt)
                oB[nt] = __builtin_amdgcn_mfma_f32_16x16x32_bf16(ua.v, vf[kk][nt], oB[nt], 0, 0, 0);
        }
        __builtin_amdgcn_s_setprio(0);

        if (actA) {
            // chain A softmax overwrites Pl[wave] (same-wave DS order -> WAR safe)
            softmax_swapped(sA, kv0 == qA0, kv0, qA0 + wave * 16, g, r, mA, lA, oA, Pl[wave]);
            asm volatile("s_waitcnt lgkmcnt(0)" ::: "memory");
            __builtin_amdgcn_s_setprio(1);
#pragma unroll
            for (int kk = 0; kk < 2; ++kk) {
                BFQ ua;
                ua.q = *(const uint4*)&Pl[wave][(r * 64 + kk * 32 + g * 8) ^ ((r & 7) << 3)];
#pragma unroll
                for (int nt = 0; nt < 4; ++nt)
                    oA[nt] = __builtin_amdgcn_mfma_f32_16x16x32_bf16(ua.v, vf[kk][nt], oA[nt], 0, 0, 0);
            }
            __builtin_amdgcn_s_setprio(0);
        }

        // drain my K staging (gl_lds) + V loads, and my Vt/P DS writes, then the
        // single per-iteration barrier publishes Vt[cur^1]/Kl[cur^1]
        asm volatile("s_waitcnt vmcnt(0) lgkmcnt(0)" ::: "memory");
        __builtin_amdgcn_s_barrier();
        cur ^= 1;
    }

    // combine per-lane l partials (one 2-shuffle reduce per chain, once)
    float lBt = lB + __shfl_xor(lB, 16);
    lBt += __shfl_xor(lBt, 32);
    float lAt = lA + __shfl_xor(lA, 16);
    lAt += __shfl_xor(lAt, 32);

    u16* OPz = z ? OP1 : OP0;
    u16* Obh = OPz + ((size_t)b * T_) * C_ + h * 64;
    float* MLz = ML + (((size_t)z * 32 + bh) * T_) * 2;
#pragma unroll
    for (int nt = 0; nt < 4; ++nt) {
#pragma unroll
        for (int j = 0; j < 4; ++j) {
            int qgB = qB0 + wave * 16 + g * 4 + j;
            Obh[(size_t)qgB * C_ + nt * 16 + r] = f2bf(oB[nt][j]);
            int qgA = qA0 + wave * 16 + g * 4 + j;
            Obh[(size_t)qgA * C_ + nt * 16 + r] = f2bf(oA[nt][j]);
        }
    }
    if (g == 0) {
        int qgB = qB0 + wave * 16 + r;
        MLz[qgB * 2 + 0] = mB;
        MLz[qgB * 2 + 1] = lBt;
        int qgA = qA0 + wave * 16 + r;
        MLz[qgA * 2 + 0] = mA;
        MLz[qgA * 2 + 1] = lAt;
    }
}

// ---------------- merge the two KV halves ----------------
__global__ void merge_kernel(const u16* __restrict__ O0, const u16* __restrict__ O1,
                             const float* __restrict__ ML, u16* __restrict__ Out) {
    int idx = blockIdx.x * blockDim.x + threadIdx.x;  // one per 8 elems
    size_t base = (size_t)idx * 8;
    int h = (int)((base >> 6) & 15);
    int q = (int)((base >> 10) & (T_ - 1));
    int b = (int)(base >> 21);
    int bh = b * 16 + h;
    const float* ml0 = ML + (((size_t)0 * 32 + bh) * T_ + q) * 2;
    const float* ml1 = ML + (((size_t)1 * 32 + bh) * T_ + q) * 2;
    float m0 = ml0[0], l0 = ml0[1];
    float m1 = ml1[0], l1 = ml1[1];
    float mM = fmaxf(m0, m1);
    float w0 = __builtin_amdgcn_exp2f(m0 - mM);
    float w1 = __builtin_amdgcn_exp2f(m1 - mM);
    float inv = 1.0f / (l0 * w0 + l1 * w1);
    BFQ a, c, o;
    a.q = *(const uint4*)(O0 + base);
    c.q = *(const uint4*)(O1 + base);
#pragma unroll
    for (int e = 0; e < 8; ++e)
        o.s[e] = f2bf((bf2f(a.s[e]) * w0 + bf2f(c.s[e]) * w1) * inv);
    *(uint4*)(Out + base) = o.q;
}

// ---------------- launcher ----------------
extern "C" void kernel_launch(void* const* d_in, const int* in_sizes, int n_in,
                              void* d_out, int out_size, void* d_ws, size_t ws_size,
                              hipStream_t stream) {
    const float* q = (const float*)d_in[0];
    const float* k = (const float*)d_in[1];
    const float* v = (const float*)d_in[2];
    // d_in[3] = mask (tril, known causal) - unused
    const float* Wq = (const float*)d_in[4];
    const float* bq = (const float*)d_in[5];
    const float* Wk = (const float*)d_in[6];
    const float* bk = (const float*)d_in[7];
    const float* Wv = (const float*)d_in[8];
    const float* bv = (const float*)d_in[9];
    const float* Wo = (const float*)d_in[10];
    const float* bo = (const float*)d_in[11];

    const size_t NTC = (size_t)B_ * T_ * C_;  // 4,194,304
    const size_t NW = (size_t)C_ * C_;        // 1,048,576

    char* ws = (char*)d_ws;
    size_t off = 0;
    u16* qb = (u16*)(ws + off);  off += NTC * 2;
    u16* kb = (u16*)(ws + off);  off += NTC * 2;
    u16* vb = (u16*)(ws + off);  off += NTC * 2;
    u16* Wqb = (u16*)(ws + off); off += NW * 2;
    u16* Wkb = (u16*)(ws + off); off += NW * 2;
    u16* Wvb = (u16*)(ws + off); off += NW * 2;
    u16* Wob = (u16*)(ws + off); off += NW * 2;
    u16* Qp = (u16*)(ws + off);  off += NTC * 2;
    u16* Kp = (u16*)(ws + off);  off += NTC * 2;
    u16* Vp = (u16*)(ws + off);  off += NTC * 2;
    u16* AOb = (u16*)(ws + off); off += NTC * 2;

    // after gemm3, qb/kb/vb are dead -> reuse for attention partials
    u16* OP0 = qb;            // unnormalized partial O, z=0 (bf16)
    u16* OP1 = kb;            // unnormalized partial O, z=1 (bf16)
    float* ML = (float*)vb;   // [z][bh][T][2] fp32 (m,l)

    cvt7_kernel<<<dim3(512, 1, 7), 256, 0, stream>>>(q, k, v, Wq, Wk, Wv, Wo,
                                                     qb, kb, vb, Wqb, Wkb, Wvb, Wob,
                                                     (int)(NTC / 4), (int)(NW / 4));

    const int M = B_ * T_;  // 4096
    dim3 g3(C_ / 64, M / 128, 3);  // (16, 32, 3) = 1536 blocks
    gemm3_kernel<<<g3, 256, 0, stream>>>(qb, kb, vb, Wqb, Wkb, Wvb, bq, bk, bv,
                                         Qp, Kp, Vp, M, C_, C_);

    attn_kernel<<<1024, 256, 0, stream>>>(Qp, Kp, Vp, OP0, OP1, ML);

    merge_kernel<<<(int)(NTC / 8 / 256), 256, 0, stream>>>(OP0, OP1, ML, AOb);

    dim3 g1(C_ / 64, M / 128, 1);
    gemm_f32_kernel<<<g1, 256, 0, stream>>>(AOb, Wob, bo, (float*)d_out, M, C_, C_);
}

// Round 20
// 128.977 us; speedup vs baseline: 1.0759x; 1.0759x over previous
//
#include <hip/hip_runtime.h>
#include <hip/hip_bf16.h>
#include <cstdint>
#include <cstddef>

#define B_ 2
#define T_ 2048
#define C_ 1024
#define H_ 16
#define D_ 64

typedef unsigned short u16;
typedef unsigned int u32;

typedef __bf16 bf16x8 __attribute__((ext_vector_type(8)));
typedef float f32x4 __attribute__((ext_vector_type(4)));

// 0.125 (1/sqrt(64)) * log2(e): QK^T then produces log2-domain scores
#define QSCALE 0.18033688011112042f
#define DEFER_THR 11.5f

union BFQ {
    uint4 q;
    bf16x8 v;
    u16 s[8];
};

__device__ __forceinline__ float bf2f(u16 s) {
    union { u32 u; float f; } x;
    x.u = ((u32)s) << 16;
    return x.f;
}

__device__ __forceinline__ u16 f2bf(float f) {  // HW RTNE
    union { __bf16 h; u16 u; } c;
    c.h = (__bf16)f;
    return c.u;
}

__device__ __forceinline__ void gl_lds16(const u16* g, u16* l) {
    __builtin_amdgcn_global_load_lds(
        (const __attribute__((address_space(1))) u32*)g,
        (__attribute__((address_space(3))) u32*)l, 16, 0, 0);
}

// ---------------- fp32 -> bf16 conversion: all 7 tensors in one launch ----------------
__global__ void cvt7_kernel(const float* __restrict__ q, const float* __restrict__ k,
                            const float* __restrict__ v, const float* __restrict__ Wq,
                            const float* __restrict__ Wk, const float* __restrict__ Wv,
                            const float* __restrict__ Wo,
                            u16* __restrict__ qb, u16* __restrict__ kb, u16* __restrict__ vb,
                            u16* __restrict__ Wqb, u16* __restrict__ Wkb, u16* __restrict__ Wvb,
                            u16* __restrict__ Wob, int nBig4, int nW4) {
    int z = blockIdx.z;
    const float* in;
    u16* out;
    int n4;
    switch (z) {
        case 0: in = q;  out = qb;  n4 = nBig4; break;
        case 1: in = k;  out = kb;  n4 = nBig4; break;
        case 2: in = v;  out = vb;  n4 = nBig4; break;
        case 3: in = Wq; out = Wqb; n4 = nW4; break;
        case 4: in = Wk; out = Wkb; n4 = nW4; break;
        case 5: in = Wv; out = Wvb; n4 = nW4; break;
        default: in = Wo; out = Wob; n4 = nW4; break;
    }
    int i = blockIdx.x * blockDim.x + threadIdx.x;
    int stride = gridDim.x * blockDim.x;
    for (; i < n4; i += stride) {
        float4 f = reinterpret_cast<const float4*>(in)[i];
        ushort4 o;
        o.x = f2bf(f.x);
        o.y = f2bf(f.y);
        o.z = f2bf(f.z);
        o.w = f2bf(f.w);
        reinterpret_cast<ushort4*>(out)[i] = o;
    }
}

// ---------------- GEMM body (R6 config): C[m,n] = sum_k A[m,k]*Bw[n,k] + bias[n]
// BM=128, BN=64, BK=64. 2-phase double-buffered LDS, both-sides XOR swizzle.
template <int OUT_BF16>
__device__ __forceinline__ void gemm_body(const u16* __restrict__ A,
                                          const u16* __restrict__ Bw,
                                          const float* __restrict__ bias,
                                          void* __restrict__ Cout,
                                          int M, int N, int K) {
    __shared__ u16 As[2][128 * 64];
    __shared__ u16 Bs[2][64 * 64];

    const int tid = threadIdx.x;
    const int lane = tid & 63;
    const int wave = tid >> 6;
    const int wm = wave >> 1, wn = wave & 1;
    const int g = lane >> 4, r = lane & 15;
    const int m0 = blockIdx.y * 128, n0 = blockIdx.x * 64;

    f32x4 acc[4][2] = {};

    const int lrow = lane >> 3;
    const int lcolS = ((lane & 7) ^ (lane >> 3)) * 8;
    const u16* Abase = A + (size_t)(m0 + lrow) * K + lcolS;
    const u16* Bbase = Bw + (size_t)(n0 + lrow) * K + lcolS;

#pragma unroll
    for (int c = 0; c < 4; ++c) {
        int ca = 4 * wave + c;
        gl_lds16(Abase + (size_t)(8 * ca) * K, As[0] + ca * 512);
    }
#pragma unroll
    for (int c = 0; c < 2; ++c) {
        int cb = 2 * wave + c;
        gl_lds16(Bbase + (size_t)(8 * cb) * K, Bs[0] + cb * 512);
    }
    __syncthreads();

    int cur = 0;
    for (int k0 = 0; k0 < K; k0 += 64) {
        if (k0 + 64 < K) {
#pragma unroll
            for (int c = 0; c < 4; ++c) {
                int ca = 4 * wave + c;
                gl_lds16(Abase + (size_t)(8 * ca) * K + k0 + 64, As[cur ^ 1] + ca * 512);
            }
#pragma unroll
            for (int c = 0; c < 2; ++c) {
                int cb = 2 * wave + c;
                gl_lds16(Bbase + (size_t)(8 * cb) * K + k0 + 64, Bs[cur ^ 1] + cb * 512);
            }
        }

#pragma unroll
        for (int kk = 0; kk < 2; ++kk) {
            bf16x8 af[4], bfv[2];
#pragma unroll
            for (int mt = 0; mt < 4; ++mt) {
                int row = wm * 64 + mt * 16 + r;
                BFQ u;
                u.q = *(const uint4*)(As[cur] + row * 64 + (((kk * 4 + g) ^ (r & 7)) * 8));
                af[mt] = u.v;
            }
#pragma unroll
            for (int nt = 0; nt < 2; ++nt) {
                int row = wn * 32 + nt * 16 + r;
                BFQ u;
                u.q = *(const uint4*)(Bs[cur] + row * 64 + (((kk * 4 + g) ^ (r & 7)) * 8));
                bfv[nt] = u.v;
            }
            __builtin_amdgcn_s_setprio(1);
#pragma unroll
            for (int mt = 0; mt < 4; ++mt)
#pragma unroll
                for (int nt = 0; nt < 2; ++nt)
                    acc[mt][nt] = __builtin_amdgcn_mfma_f32_16x16x32_bf16(af[mt], bfv[nt], acc[mt][nt], 0, 0, 0);
            __builtin_amdgcn_s_setprio(0);
        }
        __syncthreads();
        cur ^= 1;
    }

#pragma unroll
    for (int mt = 0; mt < 4; ++mt) {
#pragma unroll
        for (int nt = 0; nt < 2; ++nt) {
            int n = n0 + wn * 32 + nt * 16 + r;
            float bv = bias[n];
#pragma unroll
            for (int j = 0; j < 4; ++j) {
                int m = m0 + wm * 64 + mt * 16 + g * 4 + j;
                float val = acc[mt][nt][j] + bv;
                if (OUT_BF16)
                    ((u16*)Cout)[(size_t)m * N + n] = f2bf(val);
                else
                    ((float*)Cout)[(size_t)m * N + n] = val;
            }
        }
    }
}

__global__ __launch_bounds__(256, 3) void gemm3_kernel(
    const u16* __restrict__ A0, const u16* __restrict__ A1, const u16* __restrict__ A2,
    const u16* __restrict__ W0, const u16* __restrict__ W1, const u16* __restrict__ W2,
    const float* __restrict__ b0, const float* __restrict__ b1, const float* __restrict__ b2,
    u16* __restrict__ C0, u16* __restrict__ C1, u16* __restrict__ C2,
    int M, int N, int K) {
    int z = blockIdx.z;
    const u16* A = z == 0 ? A0 : (z == 1 ? A1 : A2);
    const u16* W = z == 0 ? W0 : (z == 1 ? W1 : W2);
    const float* bias = z == 0 ? b0 : (z == 1 ? b1 : b2);
    u16* C = z == 0 ? C0 : (z == 1 ? C1 : C2);
    gemm_body<1>(A, W, bias, C, M, N, K);
}

__global__ __launch_bounds__(256, 3) void gemm_f32_kernel(const u16* __restrict__ A,
                                                          const u16* __restrict__ W,
                                                          const float* __restrict__ bias,
                                                          float* __restrict__ C,
                                                          int M, int N, int K) {
    gemm_body<0>(A, W, bias, C, M, N, K);
}

// ---------------- causal flash attention (R18 exact: PV interleave) -----------------
// 1D grid 1024, XCD-decoded (T1). Balanced pairing (i, 31-i). Split-KV z + merge.
// Swapped QK^T -> lane-local softmax, deferred-l. Per-iteration order:
// softmaxB -> barrier -> PV B -> softmaxA -> PV A (Pl per-wave, shared buffer).

__device__ __forceinline__ void softmax_swapped(f32x4* s, int domask, int kv0, int qcol0,
                                                int g, int r, float& m_run, float& l_run,
                                                f32x4* o_acc, u16* pl) {
    float sv[4][4];
#pragma unroll
    for (int nt = 0; nt < 4; ++nt) {
#pragma unroll
        for (int j = 0; j < 4; ++j) {
            float x = s[nt][j];
            if (domask) {
                int kg = kv0 + nt * 16 + g * 4 + j;
                int qg = qcol0 + r;
                x = (kg <= qg) ? x : -1e30f;
            }
            sv[nt][j] = x;
        }
    }
    // per-lane max over this lane's 16 values (all belong to q = qcol0 + r)
    float t0 = fmaxf(fmaxf(sv[0][0], sv[0][1]), fmaxf(sv[0][2], sv[0][3]));
    float t1 = fmaxf(fmaxf(sv[1][0], sv[1][1]), fmaxf(sv[1][2], sv[1][3]));
    float t2 = fmaxf(fmaxf(sv[2][0], sv[2][1]), fmaxf(sv[2][2], sv[2][3]));
    float t3 = fmaxf(fmaxf(sv[3][0], sv[3][1]), fmaxf(sv[3][2], sv[3][3]));
    float lmax = fmaxf(fmaxf(t0, t1), fmaxf(t2, t3));

    if (!__all(lmax - m_run <= DEFER_THR)) {
        float rm = lmax;
        rm = fmaxf(rm, __shfl_xor(rm, 16));
        rm = fmaxf(rm, __shfl_xor(rm, 32));
        float mnew = fmaxf(m_run, rm);
        float fac = __builtin_amdgcn_exp2f(m_run - mnew);
        l_run *= fac;
        m_run = mnew;
#pragma unroll
        for (int j = 0; j < 4; ++j) {
            float fo = __shfl(fac, g * 4 + j);
#pragma unroll
            for (int nt = 0; nt < 4; ++nt) o_acc[nt][j] *= fo;
        }
    }

    float p[4][4];
#pragma unroll
    for (int nt = 0; nt < 4; ++nt)
#pragma unroll
        for (int j = 0; j < 4; ++j)
            p[nt][j] = __builtin_amdgcn_exp2f(sv[nt][j] - m_run);

    float s0 = (p[0][0] + p[0][1]) + (p[0][2] + p[0][3]);
    float s1 = (p[1][0] + p[1][1]) + (p[1][2] + p[1][3]);
    float s2 = (p[2][0] + p[2][1]) + (p[2][2] + p[2][3]);
    float s3 = (p[3][0] + p[3][1]) + (p[3][2] + p[3][3]);
    l_run += (s0 + s1) + (s2 + s3);

    const int sw = (r & 7) << 3;
#pragma unroll
    for (int nt = 0; nt < 4; ++nt) {
        uint2 w;
        w.x = (u32)f2bf(p[nt][0]) | ((u32)f2bf(p[nt][1]) << 16);
        w.y = (u32)f2bf(p[nt][2]) | ((u32)f2bf(p[nt][3]) << 16);
        *(uint2*)&pl[(r * 64 + nt * 16 + g * 4) ^ sw] = w;
    }
}

__global__ __launch_bounds__(256, 2) void attn_kernel(const u16* __restrict__ Qp,
                                                      const u16* __restrict__ Kp,
                                                      const u16* __restrict__ Vp,
                                                      u16* __restrict__ OP0,
                                                      u16* __restrict__ OP1,
                                                      float* __restrict__ ML) {
    __shared__ u16 Kl[2][64 * 64];   // 16KB
    __shared__ u16 Vt[64 * 64];      // 8KB
    __shared__ u16 Pl[4][16 * 64];   // 8KB: ONE per-wave P buffer, both chains

    const int tid = threadIdx.x, lane = tid & 63, wave = tid >> 6;
    const int g = lane >> 4, r = lane & 15;

    const int lid = blockIdx.x;
    const int xcd = lid & 7;
    const int idx = lid >> 3;
    const int bh = xcd * 4 + (idx >> 5);
    const int iz = idx & 31;
    const int i = iz & 15;
    const int z = iz >> 4;
    const int b = bh >> 4, h = bh & 15;
    const int qA0 = i * 64;
    const int qB0 = (31 - i) * 64;

    const u16* Qbh = Qp + ((size_t)b * T_) * C_ + h * 64;
    const u16* Kbh = Kp + ((size_t)b * T_) * C_ + h * 64;
    const u16* Vbh = Vp + ((size_t)b * T_) * C_ + h * 64;

    bf16x8 aqA[2], aqB[2];
    {
        const u16* qa = Qbh + (size_t)(qA0 + wave * 16 + r) * C_ + g * 8;
        const u16* qb = Qbh + (size_t)(qB0 + wave * 16 + r) * C_ + g * 8;
        BFQ u0, u1, u2, u3;
        u0.q = *(const uint4*)(qa);
        u1.q = *(const uint4*)(qa + 32);
        u2.q = *(const uint4*)(qb);
        u3.q = *(const uint4*)(qb + 32);
#pragma unroll
        for (int e = 0; e < 8; ++e) {
            u0.s[e] = f2bf(bf2f(u0.s[e]) * QSCALE);
            u1.s[e] = f2bf(bf2f(u1.s[e]) * QSCALE);
            u2.s[e] = f2bf(bf2f(u2.s[e]) * QSCALE);
            u3.s[e] = f2bf(bf2f(u3.s[e]) * QSCALE);
        }
        aqA[0] = u0.v; aqA[1] = u1.v;
        aqB[0] = u2.v; aqB[1] = u3.v;
    }

    float mA = -1e30f, lA = 0.f, mB = -1e30f, lB = 0.f;
    f32x4 oA[4] = {}, oB[4] = {};

    const int klr = lane >> 3;
    const int kgcol = ((lane & 7) ^ klr) * 8;

    const int vp = tid & 31;
    const int vd0 = (tid >> 5) * 8;

#pragma unroll
    for (int c = 0; c < 2; ++c) {
        int rb = wave * 16 + c * 8;
        gl_lds16(Kbh + (size_t)(z * 64 + rb + klr) * C_ + kgcol, Kl[0] + rb * 64);
    }
    BFQ va, vb;
    {
        const u16* vr0 = Vbh + (size_t)(z * 64 + 2 * vp) * C_ + vd0;
        va.q = *(const uint4*)(vr0);
        vb.q = *(const uint4*)(vr0 + C_);
    }
    asm volatile("s_waitcnt vmcnt(0)" ::: "memory");
    __builtin_amdgcn_s_barrier();

    int cur = 0;
    for (int kv0 = z * 64; kv0 <= qB0; kv0 += 128) {
        const int actA = (kv0 <= qA0);
        const int havenext = (kv0 + 128 <= qB0);

        __builtin_amdgcn_s_barrier();

        // write Vt (transposed, swizzled) from prefetched regs
#pragma unroll
        for (int ii = 0; ii < 8; ++ii) {
            int d = vd0 + ii;
            u32 pr = (u32)va.s[ii] | ((u32)vb.s[ii] << 16);
            *(u32*)&Vt[(d * 64 + 2 * vp) ^ ((d & 7) << 3)] = pr;
        }

        if (havenext) {
            const u16* vr0 = Vbh + (size_t)(kv0 + 128 + 2 * vp) * C_ + vd0;
            va.q = *(const uint4*)(vr0);
            vb.q = *(const uint4*)(vr0 + C_);
        }

        // K fragments from LDS (swizzled b128 reads)
        BFQ kf[2][4];
#pragma unroll
        for (int kk = 0; kk < 2; ++kk)
#pragma unroll
            for (int nt = 0; nt < 4; ++nt)
                kf[kk][nt].q = *(const uint4*)(Kl[cur] + (nt * 16 + r) * 64 + (((kk * 4 + g) ^ (r & 7)) * 8));

        // swapped QK^T, both chains (shared kf)
        f32x4 sB[4] = {}, sA[4] = {};
        __builtin_amdgcn_s_setprio(1);
#pragma unroll
        for (int kk = 0; kk < 2; ++kk)
#pragma unroll
            for (int nt = 0; nt < 4; ++nt)
                sB[nt] = __builtin_amdgcn_mfma_f32_16x16x32_bf16(kf[kk][nt].v, aqB[kk], sB[nt], 0, 0, 0);
        if (actA) {
#pragma unroll
            for (int kk = 0; kk < 2; ++kk)
#pragma unroll
                for (int nt = 0; nt < 4; ++nt)
                    sA[nt] = __builtin_amdgcn_mfma_f32_16x16x32_bf16(kf[kk][nt].v, aqA[kk], sA[nt], 0, 0, 0);
        }
        __builtin_amdgcn_s_setprio(0);

        // stage next K tile
        if (havenext) {
#pragma unroll
            for (int c = 0; c < 2; ++c) {
                int rb = wave * 16 + c * 8;
                gl_lds16(Kbh + (size_t)(kv0 + 128 + rb + klr) * C_ + kgcol, Kl[cur ^ 1] + rb * 64);
            }
        }

        // chain B softmax -> P in Pl[wave]
        softmax_swapped(sB, kv0 == qB0, kv0, qB0 + wave * 16, g, r, mB, lB, oB, Pl[wave]);

        asm volatile("s_waitcnt lgkmcnt(0)" ::: "memory");  // my Vt + P-B writes committed
        __builtin_amdgcn_s_barrier();                       // everyone's Vt visible

        // V fragments (shared by both chains)
        bf16x8 vf[2][4];
#pragma unroll
        for (int kk = 0; kk < 2; ++kk)
#pragma unroll
            for (int nt = 0; nt < 4; ++nt) {
                int d = nt * 16 + r;
                BFQ u;
                u.q = *(const uint4*)&Vt[(d * 64 + kk * 32 + g * 8) ^ ((d & 7) << 3)];
                vf[kk][nt] = u.v;
            }

        // PV for chain B (MFMAs overlap the upcoming softmaxA VALU chain)
        __builtin_amdgcn_s_setprio(1);
#pragma unroll
        for (int kk = 0; kk < 2; ++kk) {
            BFQ ua;
            ua.q = *(const uint4*)&Pl[wave][(r * 64 + kk * 32 + g * 8) ^ ((r & 7) << 3)];
#pragma unroll
            for (int nt = 0; nt < 4; ++nt)
                oB[nt] = __builtin_amdgcn_mfma_f32_16x16x32_bf16(ua.v, vf[kk][nt], oB[nt], 0, 0, 0);
        }
        __builtin_amdgcn_s_setprio(0);

        if (actA) {
            // chain A softmax overwrites Pl[wave] (same-wave DS ops retire in
            // order: P-A writes issue after PV-B's Pl reads -> WAR safe)
            softmax_swapped(sA, kv0 == qA0, kv0, qA0 + wave * 16, g, r, mA, lA, oA, Pl[wave]);
            asm volatile("s_waitcnt lgkmcnt(0)" ::: "memory");  // P-A visible to my reads
            __builtin_amdgcn_s_setprio(1);
#pragma unroll
            for (int kk = 0; kk < 2; ++kk) {
                BFQ ua;
                ua.q = *(const uint4*)&Pl[wave][(r * 64 + kk * 32 + g * 8) ^ ((r & 7) << 3)];
#pragma unroll
                for (int nt = 0; nt < 4; ++nt)
                    oA[nt] = __builtin_amdgcn_mfma_f32_16x16x32_bf16(ua.v, vf[kk][nt], oA[nt], 0, 0, 0);
            }
            __builtin_amdgcn_s_setprio(0);
        }

        asm volatile("s_waitcnt vmcnt(0)" ::: "memory");
        cur ^= 1;
    }

    // combine per-lane l partials (one 2-shuffle reduce per chain, once)
    float lBt = lB + __shfl_xor(lB, 16);
    lBt += __shfl_xor(lBt, 32);
    float lAt = lA + __shfl_xor(lA, 16);
    lAt += __shfl_xor(lAt, 32);

    u16* OPz = z ? OP1 : OP0;
    u16* Obh = OPz + ((size_t)b * T_) * C_ + h * 64;
    float* MLz = ML + (((size_t)z * 32 + bh) * T_) * 2;
#pragma unroll
    for (int nt = 0; nt < 4; ++nt) {
#pragma unroll
        for (int j = 0; j < 4; ++j) {
            int qgB = qB0 + wave * 16 + g * 4 + j;
            Obh[(size_t)qgB * C_ + nt * 16 + r] = f2bf(oB[nt][j]);
            int qgA = qA0 + wave * 16 + g * 4 + j;
            Obh[(size_t)qgA * C_ + nt * 16 + r] = f2bf(oA[nt][j]);
        }
    }
    if (g == 0) {
        int qgB = qB0 + wave * 16 + r;
        MLz[qgB * 2 + 0] = mB;
        MLz[qgB * 2 + 1] = lBt;
        int qgA = qA0 + wave * 16 + r;
        MLz[qgA * 2 + 0] = mA;
        MLz[qgA * 2 + 1] = lAt;
    }
}

// ---------------- merge the two KV halves ----------------
__global__ void merge_kernel(const u16* __restrict__ O0, const u16* __restrict__ O1,
                             const float* __restrict__ ML, u16* __restrict__ Out) {
    int idx = blockIdx.x * blockDim.x + threadIdx.x;  // one per 8 elems
    size_t base = (size_t)idx * 8;
    int h = (int)((base >> 6) & 15);
    int q = (int)((base >> 10) & (T_ - 1));
    int b = (int)(base >> 21);
    int bh = b * 16 + h;
    const float* ml0 = ML + (((size_t)0 * 32 + bh) * T_ + q) * 2;
    const float* ml1 = ML + (((size_t)1 * 32 + bh) * T_ + q) * 2;
    float m0 = ml0[0], l0 = ml0[1];
    float m1 = ml1[0], l1 = ml1[1];
    float mM = fmaxf(m0, m1);
    float w0 = __builtin_amdgcn_exp2f(m0 - mM);
    float w1 = __builtin_amdgcn_exp2f(m1 - mM);
    float inv = 1.0f / (l0 * w0 + l1 * w1);
    BFQ a, c, o;
    a.q = *(const uint4*)(O0 + base);
    c.q = *(const uint4*)(O1 + base);
#pragma unroll
    for (int e = 0; e < 8; ++e)
        o.s[e] = f2bf((bf2f(a.s[e]) * w0 + bf2f(c.s[e]) * w1) * inv);
    *(uint4*)(Out + base) = o.q;
}

// ---------------- launcher ----------------
extern "C" void kernel_launch(void* const* d_in, const int* in_sizes, int n_in,
                              void* d_out, int out_size, void* d_ws, size_t ws_size,
                              hipStream_t stream) {
    const float* q = (const float*)d_in[0];
    const float* k = (const float*)d_in[1];
    const float* v = (const float*)d_in[2];
    // d_in[3] = mask (tril, known causal) - unused
    const float* Wq = (const float*)d_in[4];
    const float* bq = (const float*)d_in[5];
    const float* Wk = (const float*)d_in[6];
    const float* bk = (const float*)d_in[7];
    const float* Wv = (const float*)d_in[8];
    const float* bv = (const float*)d_in[9];
    const float* Wo = (const float*)d_in[10];
    const float* bo = (const float*)d_in[11];

    const size_t NTC = (size_t)B_ * T_ * C_;  // 4,194,304
    const size_t NW = (size_t)C_ * C_;        // 1,048,576

    char* ws = (char*)d_ws;
    size_t off = 0;
    u16* qb = (u16*)(ws + off);  off += NTC * 2;
    u16* kb = (u16*)(ws + off);  off += NTC * 2;
    u16* vb = (u16*)(ws + off);  off += NTC * 2;
    u16* Wqb = (u16*)(ws + off); off += NW * 2;
    u16* Wkb = (u16*)(ws + off); off += NW * 2;
    u16* Wvb = (u16*)(ws + off); off += NW * 2;
    u16* Wob = (u16*)(ws + off); off += NW * 2;
    u16* Qp = (u16*)(ws + off);  off += NTC * 2;
    u16* Kp = (u16*)(ws + off);  off += NTC * 2;
    u16* Vp = (u16*)(ws + off);  off += NTC * 2;
    u16* AOb = (u16*)(ws + off); off += NTC * 2;

    // after gemm3, qb/kb/vb are dead -> reuse for attention partials
    u16* OP0 = qb;            // unnormalized partial O, z=0 (bf16)
    u16* OP1 = kb;            // unnormalized partial O, z=1 (bf16)
    float* ML = (float*)vb;   // [z][bh][T][2] fp32 (m,l)

    cvt7_kernel<<<dim3(512, 1, 7), 256, 0, stream>>>(q, k, v, Wq, Wk, Wv, Wo,
                                                     qb, kb, vb, Wqb, Wkb, Wvb, Wob,
                                                     (int)(NTC / 4), (int)(NW / 4));

    const int M = B_ * T_;  // 4096
    dim3 g3(C_ / 64, M / 128, 3);  // (16, 32, 3) = 1536 blocks
    gemm3_kernel<<<g3, 256, 0, stream>>>(qb, kb, vb, Wqb, Wkb, Wvb, bq, bk, bv,
                                         Qp, Kp, Vp, M, C_, C_);

    attn_kernel<<<1024, 256, 0, stream>>>(Qp, Kp, Vp, OP0, OP1, ML);

    merge_kernel<<<(int)(NTC / 8 / 256), 256, 0, stream>>>(OP0, OP1, ML, AOb);

    dim3 g1(C_ / 64, M / 128, 1);
    gemm_f32_kernel<<<g1, 256, 0, stream>>>(AOb, Wob, bo, (float*)d_out, M, C_, C_);
}